// Round 8
// baseline (78.602 us; speedup 1.0000x reference)
//
#include <hip/hip_runtime.h>
#include <math.h>

#define D      128
#define CCLS   64
#define SLP    68   // padded LDS row stride (floats)
#define CHUNKS 8

typedef _Float16 f16x8 __attribute__((ext_vector_type(8)));
typedef _Float16 f16x4 __attribute__((ext_vector_type(4)));
typedef float    f32x4 __attribute__((ext_vector_type(4)));

__device__ __forceinline__ float wave_reduce_sum(float v) {
    #pragma unroll
    for (int off = 32; off > 0; off >>= 1) v += __shfl_xor(v, off, 64);
    return v;
}

// --- class histogram: ONE block, LDS atomics only ---------------------------
__global__ void hist_kernel(const int* __restrict__ t2, const int* __restrict__ t3,
                            float* __restrict__ cls_freq, int N, int M) {
    __shared__ int h[CCLS];
    int t = threadIdx.x;
    if (t < CCLS) h[t] = 0;
    __syncthreads();
    for (int i = t; i < M; i += blockDim.x) {
        int lab = (i < N) ? t2[i] : t3[i - N];
        atomicAdd(&h[lab], 1);
    }
    __syncthreads();
    if (t < CCLS) cls_freq[t] = (float)h[t] + 1.0f + 1e-6f;
}

// --- normalize rows (feats ++ protos ++ zero-pad), fold sqrt(log2e/TAU),
//     cast f16, MFMA-tiled layout: elem(r,k) ->
//     ((r>>4)*16 + (k>>3))*128 + (r&15)*8 + (k&7).  One wave per row.
//     ALSO: first 2048 waves build one-hot tiles in 16x16x16 B-frag layout.
__global__ void norm_kernel(const float* __restrict__ protos,
                            const float* __restrict__ proj2,
                            const float* __restrict__ proj3,
                            const int* __restrict__ t2, const int* __restrict__ t3,
                            _Float16* __restrict__ ftile,
                            _Float16* __restrict__ oh, int N, int M) {
    const float SCL = 3.8017368953f;  // sqrt(10 * log2(e))
    int w = threadIdx.x >> 6;
    int lane = threadIdx.x & 63;
    int g = lane >> 4, li = lane & 15;
    int row = blockIdx.x * (blockDim.x >> 6) + w;
    const int MT = M + 128;

    if (row < MT) {
        const float* src = nullptr;
        if (row < M)             src = (row < N) ? proj2 + (size_t)row * D
                                                 : proj3 + (size_t)(row - N) * D;
        else if (row < M + CCLS) src = protos + (size_t)(row - M) * D;
        float2 v = {0.f, 0.f};
        if (src) v = ((const float2*)src)[lane];
        float ss = wave_reduce_sum(v.x * v.x + v.y * v.y);
        float scale = src ? SCL / fmaxf(sqrtf(ss), 1e-12f) : 0.f;
        _Float16 h0 = (_Float16)(v.x * scale), h1 = (_Float16)(v.y * scale);
        int k0 = 2 * lane;
        size_t off = ((size_t)(row >> 4) * 16 + (k0 >> 3)) * 128 + (row & 15) * 8 + (k0 & 7);
        ftile[off] = h0; ftile[off + 1] = h1;
    }

    int wid = blockIdx.x * (blockDim.x >> 6) + w;
    if (wid < (M / 16) * 4) {
        int jt = wid >> 2, ct = wid & 3;
        int c = ct * 16 + li;
        f16x4 v;
        #pragma unroll
        for (int e = 0; e < 4; ++e) {
            int j = jt * 16 + 4 * g + e;
            int labj = (j < N) ? t2[j] : t3[j - N];
            v[e] = (labj == c) ? (_Float16)1.0f : (_Float16)0.0f;
        }
        *(f16x4*)(oh + ((size_t)(jt * 4 + ct)) * 256 + lane * 4) = v;
    }
}

// --- main: panel (64 rows) x chunk (16 slices) per block, grid 128x8 =
//     1024 blocks (4/CU, 16 waves/CU) for latency hiding. 4 waves:
//     wave = (row-half ro, slice-half). Per wave: 32 rows, 8 slices.
//     Stage1: mfma_16x16x32_f16 (swapped) -> P tile (i=li, j=16n+4g+r).
//     exp2 -> cvt_pkrtz -> stage2 A-frag. Stage2: S[i][c] += P*onehot on
//     the MFMA pipe. ALL register arrays statically indexed (rule #20).
__global__ __launch_bounds__(256, 4)
void sim_kernel(const _Float16* __restrict__ ftile,
                const _Float16* __restrict__ oh,
                float* __restrict__ Spart, float* __restrict__ E, int M) {
    __shared__ float Sl[64][SLP];

    const int panel = blockIdx.x;           // [0, M/64)
    const int chunk = blockIdx.y;           // [0, CHUNKS)
    const int t = threadIdx.x;
    const int w = t >> 6, lane = t & 63;
    const int g = lane >> 4, li = lane & 15;
    const int lo = g * 128 + li * 8;
    const int ro = (w & 1) * 32;            // row offset within panel
    const int half = w >> 1;                // slice half
    const int rtA = panel * 4 + (ro >> 4);
    const int ndBase = ro >> 4;             // 0 or 2

    // A fragments: this wave's 32 rows x 128 k (32 VGPRs)
    f16x8 a[2][4];
    #pragma unroll
    for (int m = 0; m < 2; ++m)
        #pragma unroll
        for (int kt = 0; kt < 4; ++kt)
            a[m][kt] = *(const f16x8*)(ftile + (size_t)(rtA + m) * 2048 + kt * 512 + lo);

    f32x4 acc2[2][4];                       // i = ro+16m+4g+r, c = 16nc+li
    #pragma unroll
    for (int m = 0; m < 2; ++m)
        #pragma unroll
        for (int nc = 0; nc < 4; ++nc)
            #pragma unroll
            for (int r = 0; r < 4; ++r) acc2[m][nc][r] = 0.f;

    const int sBase = chunk * (128 / CHUNKS) + half * (64 / CHUNKS);
    for (int si = 0; si < 64 / CHUNKS; ++si) {
        const int s = sBase + si;
        const int rb0 = s * 4;

        f32x4 acc1[2][4];
        #pragma unroll
        for (int m = 0; m < 2; ++m)
            #pragma unroll
            for (int n = 0; n < 4; ++n)
                #pragma unroll
                for (int r = 0; r < 4; ++r) acc1[m][n][r] = 0.f;

        #pragma unroll
        for (int kt = 0; kt < 4; ++kt) {
            f16x8 b[4];
            #pragma unroll
            for (int n = 0; n < 4; ++n)
                b[n] = *(const f16x8*)(ftile + (size_t)(rb0 + n) * 2048 + kt * 512 + lo);
            #pragma unroll
            for (int m = 0; m < 2; ++m)
                #pragma unroll
                for (int n = 0; n < 4; ++n)
                    acc1[m][n] = __builtin_amdgcn_mfma_f32_16x16x32_f16(b[n], a[m][kt], acc1[m][n], 0, 0, 0);
        }

        // diagonal mask: STATIC indices, runtime predicate (v_cndmask)
        if (s == panel) {
            #pragma unroll
            for (int m = 0; m < 2; ++m)
                #pragma unroll
                for (int n = 0; n < 4; ++n)
                    #pragma unroll
                    for (int r = 0; r < 4; ++r)
                        acc1[m][n][r] = (n == ndBase + m && 4 * g + r == li)
                                        ? -1e5f : acc1[m][n][r];
        }

        #pragma unroll
        for (int n = 0; n < 4; ++n) {
            f16x4 pa[2];
            #pragma unroll
            for (int m = 0; m < 2; ++m) {
                auto l2 = __builtin_amdgcn_cvt_pkrtz(exp2f(acc1[m][n][0]), exp2f(acc1[m][n][1]));
                auto h2 = __builtin_amdgcn_cvt_pkrtz(exp2f(acc1[m][n][2]), exp2f(acc1[m][n][3]));
                f16x4 p; p.x = l2.x; p.y = l2.y; p.z = h2.x; p.w = h2.y;
                pa[m] = p;
            }
            #pragma unroll
            for (int nc = 0; nc < 4; ++nc) {
                f16x4 ohf = *(const f16x4*)(oh + ((size_t)(s * 4 + n) * 4 + nc) * 256 + lane * 4);
                #pragma unroll
                for (int m = 0; m < 2; ++m)
                    acc2[m][nc] = __builtin_amdgcn_mfma_f32_16x16x16f16(pa[m], ohf, acc2[m][nc], 0, 0, 0);
            }
        }
    }

    // pair-reduce: half0 writes LDS; half1 adds and stores chunk partial
    if (half == 0) {
        #pragma unroll
        for (int m = 0; m < 2; ++m)
            #pragma unroll
            for (int nc = 0; nc < 4; ++nc)
                #pragma unroll
                for (int r = 0; r < 4; ++r)
                    Sl[ro + 16 * m + 4 * g + r][nc * 16 + li] = acc2[m][nc][r];
    }
    __syncthreads();
    if (half == 1) {
        float* dst = Spart + ((size_t)chunk * gridDim.x + panel) * 4096;
        #pragma unroll
        for (int m = 0; m < 2; ++m)
            #pragma unroll
            for (int nc = 0; nc < 4; ++nc)
                #pragma unroll
                for (int r = 0; r < 4; ++r) {
                    const int row = ro + 16 * m + 4 * g + r, c = nc * 16 + li;
                    dst[(size_t)row * 64 + c] = acc2[m][nc][r] + Sl[row][c];
                }
    }

    // proto slice: chunk 0, half 0 waves (both row halves), E[i][c] direct
    if (chunk == 0 && half == 0) {
        const int rbp = M >> 4;
        f32x4 accp[2][4];
        #pragma unroll
        for (int m = 0; m < 2; ++m)
            #pragma unroll
            for (int n = 0; n < 4; ++n)
                #pragma unroll
                for (int r = 0; r < 4; ++r) accp[m][n][r] = 0.f;
        #pragma unroll
        for (int kt = 0; kt < 4; ++kt) {
            f16x8 b[4];
            #pragma unroll
            for (int n = 0; n < 4; ++n)
                b[n] = *(const f16x8*)(ftile + (size_t)(rbp + n) * 2048 + kt * 512 + lo);
            #pragma unroll
            for (int m = 0; m < 2; ++m)
                #pragma unroll
                for (int n = 0; n < 4; ++n)
                    accp[m][n] = __builtin_amdgcn_mfma_f32_16x16x32_f16(b[n], a[m][kt], accp[m][n], 0, 0, 0);
        }
        #pragma unroll
        for (int m = 0; m < 2; ++m)
            #pragma unroll
            for (int n = 0; n < 4; ++n)
                #pragma unroll
                for (int r = 0; r < 4; ++r)
                    E[(size_t)(panel * 64 + ro + 16 * m + li) * 64 + n * 16 + 4 * g + r]
                        = exp2f(accp[m][n][r]);
    }
}

// --- per-row loss: one wave per row, lane = class ---------------------------
__global__ void fin_kernel(const int* __restrict__ t2, const int* __restrict__ t3,
                           const float* __restrict__ cls_freq,
                           const float* __restrict__ Spart, const float* __restrict__ E,
                           float* __restrict__ loss, int N, int M) {
    int w = threadIdx.x >> 6, lane = threadIdx.x & 63;
    int i = blockIdx.x * (blockDim.x >> 6) + w;
    if (i >= M) return;
    const int panel = i >> 6, lrow = i & 63;
    const size_t pbase = (size_t)panel * 4096 + (size_t)lrow * 64 + lane;
    const size_t cstride = (size_t)(M / 64) * 4096;
    float s = 0.f;
    #pragma unroll
    for (int k = 0; k < CHUNKS; ++k) s += Spart[pbase + (size_t)k * cstride];
    float ev = E[(size_t)i * 64 + lane];
    float fr = cls_freq[lane];
    float sumS  = wave_reduce_sum(s);
    float sumEw = wave_reduce_sum(ev / fr);
    int lab = (i < N) ? t2[i] : t3[i - N];
    float nmr = __shfl(s + ev, lab, 64);
    float fl  = __shfl(fr, lab, 64);
    float denom = sumS / fl + sumEw;
    if (lane == 0) loss[i] = logf(denom + 1e-12f) - logf(nmr);
}

// --- mean reduction: one block -----------------------------------------------
__global__ void out_kernel(const float* __restrict__ loss, float* __restrict__ out, int M) {
    float s = 0.f;
    for (int i = threadIdx.x; i < M; i += 1024) s += loss[i];
    s = wave_reduce_sum(s);
    __shared__ float ws_[16];
    if ((threadIdx.x & 63) == 0) ws_[threadIdx.x >> 6] = s;
    __syncthreads();
    if (threadIdx.x == 0) {
        float t = 0.f;
        for (int k = 0; k < 16; ++k) t += ws_[k];
        out[0] = t / (float)M;
    }
}

extern "C" void kernel_launch(void* const* d_in, const int* in_sizes, int n_in,
                              void* d_out, int out_size, void* d_ws, size_t ws_size,
                              hipStream_t stream) {
    const float* protos = (const float*)d_in[0];
    const float* proj2  = (const float*)d_in[1];
    const int*   t2     = (const int*)d_in[2];
    const float* proj3  = (const float*)d_in[3];
    const int*   t3     = (const int*)d_in[4];
    float* out = (float*)d_out;

    const int N = in_sizes[1] / D;   // 4096
    const int M = 2 * N;             // 8192
    const int MT = M + 128;

    _Float16* ftile = (_Float16*)d_ws;                          // MT*D halfs
    _Float16* oh    = ftile + (size_t)MT * D;                   // (M/16)*4*256 halfs
    float* Spart    = (float*)(oh + (size_t)(M / 16) * 4 * 256); // CHUNKS*(M/64)*4096
    float* E        = Spart + (size_t)CHUNKS * (M / 64) * 4096; // M*64
    float* loss     = E + (size_t)M * 64;                       // M
    float* cls_freq = loss + M;                                 // 64

    hist_kernel<<<1, 1024, 0, stream>>>(t2, t3, cls_freq, N, M);
    norm_kernel<<<(MT + 3) / 4, 256, 0, stream>>>(protos, proj2, proj3, t2, t3,
                                                  ftile, oh, N, M);
    dim3 grid(M / 64, CHUNKS);
    sim_kernel<<<grid, 256, 0, stream>>>(ftile, oh, Spart, E, M);
    fin_kernel<<<(M + 3) / 4, 256, 0, stream>>>(t2, t3, cls_freq, Spart, E, loss, N, M);
    out_kernel<<<1, 1024, 0, stream>>>(loss, out, M);
}

// Round 9
// 54.492 us; speedup vs baseline: 1.4424x; 1.4424x over previous
//
#include <hip/hip_runtime.h>
#include <math.h>
#include <stdint.h>

#define D    128
#define CCLS 64
#define CH   8      // column chunks; grid = (M/128) x CH

typedef _Float16 f16x8 __attribute__((ext_vector_type(8)));
typedef _Float16 f16x4 __attribute__((ext_vector_type(4)));
typedef float    f32x4 __attribute__((ext_vector_type(4)));

__device__ __forceinline__ float wave_reduce_sum(float v) {
    #pragma unroll
    for (int off = 32; off > 0; off >>= 1) v += __shfl_xor(v, off, 64);
    return v;
}

__device__ __forceinline__ void gload_lds16(const void* g, void* l) {
    __builtin_amdgcn_global_load_lds(
        (const __attribute__((address_space(1))) uint32_t*)g,
        (__attribute__((address_space(3))) uint32_t*)l, 16, 0, 0);
}

// --- class histogram: ONE block, LDS atomics only ---------------------------
__global__ void hist_kernel(const int* __restrict__ t2, const int* __restrict__ t3,
                            float* __restrict__ cls_freq, int N, int M) {
    __shared__ int h[CCLS];
    int t = threadIdx.x;
    if (t < CCLS) h[t] = 0;
    __syncthreads();
    for (int i = t; i < M; i += blockDim.x) {
        int lab = (i < N) ? t2[i] : t3[i - N];
        atomicAdd(&h[lab], 1);
    }
    __syncthreads();
    if (t < CCLS) cls_freq[t] = (float)h[t] + 1.0f + 1e-6f;
}

// --- normalize rows (feats ++ protos ++ zero-pad), fold sqrt(log2e/TAU),
//     cast f16, MFMA-tiled layout: elem(r,k) ->
//     ((r>>4)*16 + (k>>3))*128 + (r&15)*8 + (k&7).  One wave per row.
//     ALSO: first 2048 waves build one-hot tiles in 16x16x16 B-frag layout.
__global__ void norm_kernel(const float* __restrict__ protos,
                            const float* __restrict__ proj2,
                            const float* __restrict__ proj3,
                            const int* __restrict__ t2, const int* __restrict__ t3,
                            _Float16* __restrict__ ftile,
                            _Float16* __restrict__ oh, int N, int M) {
    const float SCL = 3.8017368953f;  // sqrt(10 * log2(e))
    int w = threadIdx.x >> 6;
    int lane = threadIdx.x & 63;
    int g = lane >> 4, li = lane & 15;
    int row = blockIdx.x * (blockDim.x >> 6) + w;
    const int MT = M + 128;

    if (row < MT) {
        const float* src = nullptr;
        if (row < M)             src = (row < N) ? proj2 + (size_t)row * D
                                                 : proj3 + (size_t)(row - N) * D;
        else if (row < M + CCLS) src = protos + (size_t)(row - M) * D;
        float2 v = {0.f, 0.f};
        if (src) v = ((const float2*)src)[lane];
        float ss = wave_reduce_sum(v.x * v.x + v.y * v.y);
        float scale = src ? SCL / fmaxf(sqrtf(ss), 1e-12f) : 0.f;
        _Float16 h0 = (_Float16)(v.x * scale), h1 = (_Float16)(v.y * scale);
        int k0 = 2 * lane;
        size_t off = ((size_t)(row >> 4) * 16 + (k0 >> 3)) * 128 + (row & 15) * 8 + (k0 & 7);
        ftile[off] = h0; ftile[off + 1] = h1;
    }

    int wid = blockIdx.x * (blockDim.x >> 6) + w;
    if (wid < (M / 16) * 4) {
        int jt = wid >> 2, ct = wid & 3;
        int c = ct * 16 + li;
        f16x4 v;
        #pragma unroll
        for (int e = 0; e < 4; ++e) {
            int j = jt * 16 + 4 * g + e;
            int labj = (j < N) ? t2[j] : t3[j - N];
            v[e] = (labj == c) ? (_Float16)1.0f : (_Float16)0.0f;
        }
        *(f16x4*)(oh + ((size_t)(jt * 4 + ct)) * 256 + lane * 4) = v;
    }
}

// --- main: 128-row panel per block.x, 16-slice chunk per block.y.
//     4 waves = 4 disjoint 32-row groups, ALL processing the same slices:
//     B-tile (16KB) + oh-tile (8KB) staged per slice via global_load_lds,
//     double-buffered, shared by the whole block (4x less L2 traffic).
//     Stage1: mfma_16x16x32_f16 (swapped) -> P (i=li, j=16n+4g+r);
//     exp2 -> cvt_pkrtz -> stage2 A-frag; stage2 16x16x16 vs onehot -> S.
//     Waves own disjoint rows => acc2 stored directly (no LDS reduce).
__global__ __launch_bounds__(256, 2)
void sim_kernel(const _Float16* __restrict__ ftile,
                const _Float16* __restrict__ ohtab,
                float* __restrict__ Spart, float* __restrict__ E, int M) {
    __shared__ _Float16 sbuf[2][12288];   // per buf: [0,8192)=B, [8192,12288)=oh

    const int panel = blockIdx.x;         // [0, M/128)
    const int chunk = blockIdx.y;         // [0, CH)
    const int t = threadIdx.x;
    const int w = t >> 6, lane = t & 63;
    const int g = lane >> 4, li = lane & 15;
    const int lo = g * 128 + li * 8;
    const int rtA = panel * 8 + w * 2;    // wave's two 16-row A tiles
    const int nS = (M / 64) / CH;         // 16 slices per chunk
    const int sBase = chunk * nS;

    // A fragments: this wave's 32 rows x 128 k
    f16x8 a[2][4];
    #pragma unroll
    for (int m = 0; m < 2; ++m)
        #pragma unroll
        for (int kt = 0; kt < 4; ++kt)
            a[m][kt] = *(const f16x8*)(ftile + (size_t)(rtA + m) * 2048 + kt * 512 + lo);

    f32x4 acc2[2][4];                     // i = 32w+16m+4g+r, c = 16nc+li
    #pragma unroll
    for (int m = 0; m < 2; ++m)
        #pragma unroll
        for (int nc = 0; nc < 4; ++nc)
            #pragma unroll
            for (int r = 0; r < 4; ++r) acc2[m][nc][r] = 0.f;

    // ---- staging: 24 x 1KB wave-issues per slice; wave w does j = 6w..6w+5
    #define STAGE(buf, s)                                                        \
        {                                                                        \
            const char* bsrc_ = (const char*)ftile + (size_t)(s) * 16384;        \
            const char* osrc_ = (const char*)ohtab + (size_t)(s) * 8192;         \
            char* dst_ = (char*)&sbuf[(buf)][0];                                 \
            _Pragma("unroll")                                                    \
            for (int q = 0; q < 6; ++q) {                                        \
                int j_ = w * 6 + q;                                              \
                const char* src_ = (j_ < 16)                                     \
                    ? bsrc_ + (size_t)j_ * 1024 + lane * 16                      \
                    : osrc_ + (size_t)(j_ - 16) * 1024 + lane * 16;              \
                gload_lds16(src_, dst_ + (size_t)j_ * 1024);                     \
            }                                                                    \
        }

    STAGE(0, sBase);
    __syncthreads();                       // compiler drains vmcnt before barrier
    int cur = 0;

    const int diagS = 2 * panel + (w >> 1);   // slice containing this wave's rows
    const int nDiag = 2 * (w & 1);            // n == nDiag + m on that slice

    for (int si = 0; si < nS; ++si) {
        const int s = sBase + si;
        if (si + 1 < nS) STAGE(cur ^ 1, sBase + si + 1);

        const _Float16* Bl = &sbuf[cur][0];
        const _Float16* Ol = &sbuf[cur][8192];

        f32x4 acc1[2][4];
        #pragma unroll
        for (int m = 0; m < 2; ++m)
            #pragma unroll
            for (int n = 0; n < 4; ++n)
                #pragma unroll
                for (int r = 0; r < 4; ++r) acc1[m][n][r] = 0.f;

        #pragma unroll
        for (int kt = 0; kt < 4; ++kt) {
            f16x8 b[4];
            #pragma unroll
            for (int n = 0; n < 4; ++n)
                b[n] = *(const f16x8*)(Bl + n * 2048 + kt * 512 + lo);
            #pragma unroll
            for (int m = 0; m < 2; ++m)
                #pragma unroll
                for (int n = 0; n < 4; ++n)
                    acc1[m][n] = __builtin_amdgcn_mfma_f32_16x16x32_f16(b[n], a[m][kt], acc1[m][n], 0, 0, 0);
        }

        // diagonal mask: wave-uniform slice test, static indices, cndmask
        if (s == diagS) {
            #pragma unroll
            for (int m = 0; m < 2; ++m)
                #pragma unroll
                for (int n = 0; n < 4; ++n)
                    #pragma unroll
                    for (int r = 0; r < 4; ++r)
                        acc1[m][n][r] = (n == nDiag + m && 4 * g + r == li)
                                        ? -1e5f : acc1[m][n][r];
        }

        #pragma unroll
        for (int n = 0; n < 4; ++n) {
            f16x4 pa[2];
            #pragma unroll
            for (int m = 0; m < 2; ++m) {
                auto l2 = __builtin_amdgcn_cvt_pkrtz(__builtin_amdgcn_exp2f(acc1[m][n][0]),
                                                     __builtin_amdgcn_exp2f(acc1[m][n][1]));
                auto h2 = __builtin_amdgcn_cvt_pkrtz(__builtin_amdgcn_exp2f(acc1[m][n][2]),
                                                     __builtin_amdgcn_exp2f(acc1[m][n][3]));
                f16x4 p; p.x = l2.x; p.y = l2.y; p.z = h2.x; p.w = h2.y;
                pa[m] = p;
            }
            #pragma unroll
            for (int nc = 0; nc < 4; ++nc) {
                f16x4 ohf = *(const f16x4*)(Ol + (n * 4 + nc) * 256 + lane * 4);
                #pragma unroll
                for (int m = 0; m < 2; ++m)
                    acc2[m][nc] = __builtin_amdgcn_mfma_f32_16x16x16f16(pa[m], ohf, acc2[m][nc], 0, 0, 0);
            }
        }

        __syncthreads();                   // drains stage loads + LDS reads
        cur ^= 1;
    }

    // store this wave's 32x64 partial directly (rows disjoint per wave)
    {
        float* dst = Spart + ((size_t)chunk * gridDim.x + panel) * (128 * 64);
        #pragma unroll
        for (int m = 0; m < 2; ++m)
            #pragma unroll
            for (int nc = 0; nc < 4; ++nc)
                #pragma unroll
                for (int r = 0; r < 4; ++r)
                    dst[(size_t)(32 * w + 16 * m + 4 * g + r) * 64 + nc * 16 + li]
                        = acc2[m][nc][r];
    }

    // proto slice: chunk-0 blocks, all 4 waves (disjoint rows) -> E[i][c]
    if (chunk == 0) {
        const int rbp = M >> 4;
        f32x4 accp[2][4];
        #pragma unroll
        for (int m = 0; m < 2; ++m)
            #pragma unroll
            for (int n = 0; n < 4; ++n)
                #pragma unroll
                for (int r = 0; r < 4; ++r) accp[m][n][r] = 0.f;
        #pragma unroll
        for (int kt = 0; kt < 4; ++kt) {
            f16x8 b[4];
            #pragma unroll
            for (int n = 0; n < 4; ++n)
                b[n] = *(const f16x8*)(ftile + (size_t)(rbp + n) * 2048 + kt * 512 + lo);
            #pragma unroll
            for (int m = 0; m < 2; ++m)
                #pragma unroll
                for (int n = 0; n < 4; ++n)
                    accp[m][n] = __builtin_amdgcn_mfma_f32_16x16x32_f16(b[n], a[m][kt], accp[m][n], 0, 0, 0);
        }
        #pragma unroll
        for (int m = 0; m < 2; ++m)
            #pragma unroll
            for (int n = 0; n < 4; ++n)
                #pragma unroll
                for (int r = 0; r < 4; ++r)
                    E[(size_t)(panel * 128 + 32 * w + 16 * m + li) * 64 + n * 16 + 4 * g + r]
                        = __builtin_amdgcn_exp2f(accp[m][n][r]);
    }
}

// --- per-row loss: one wave per row, lane = class ---------------------------
__global__ void fin_kernel(const int* __restrict__ t2, const int* __restrict__ t3,
                           const float* __restrict__ cls_freq,
                           const float* __restrict__ Spart, const float* __restrict__ E,
                           float* __restrict__ loss, int N, int M) {
    int w = threadIdx.x >> 6, lane = threadIdx.x & 63;
    int i = blockIdx.x * (blockDim.x >> 6) + w;
    if (i >= M) return;
    const int panel = i >> 7, lrow = i & 127;
    const size_t pbase = (size_t)panel * (128 * 64) + (size_t)lrow * 64 + lane;
    const size_t cstride = (size_t)(M / 128) * (128 * 64);
    float s = 0.f;
    #pragma unroll
    for (int k = 0; k < CH; ++k) s += Spart[pbase + (size_t)k * cstride];
    float ev = E[(size_t)i * 64 + lane];
    float fr = cls_freq[lane];
    float sumS  = wave_reduce_sum(s);
    float sumEw = wave_reduce_sum(ev / fr);
    int lab = (i < N) ? t2[i] : t3[i - N];
    float nmr = __shfl(s + ev, lab, 64);
    float fl  = __shfl(fr, lab, 64);
    float denom = sumS / fl + sumEw;
    if (lane == 0) loss[i] = logf(denom + 1e-12f) - logf(nmr);
}

// --- mean reduction: one block ----------------------------------------------
__global__ void out_kernel(const float* __restrict__ loss, float* __restrict__ out, int M) {
    float s = 0.f;
    for (int i = threadIdx.x; i < M; i += 1024) s += loss[i];
    s = wave_reduce_sum(s);
    __shared__ float ws_[16];
    if ((threadIdx.x & 63) == 0) ws_[threadIdx.x >> 6] = s;
    __syncthreads();
    if (threadIdx.x == 0) {
        float t = 0.f;
        for (int k = 0; k < 16; ++k) t += ws_[k];
        out[0] = t / (float)M;
    }
}

extern "C" void kernel_launch(void* const* d_in, const int* in_sizes, int n_in,
                              void* d_out, int out_size, void* d_ws, size_t ws_size,
                              hipStream_t stream) {
    const float* protos = (const float*)d_in[0];
    const float* proj2  = (const float*)d_in[1];
    const int*   t2     = (const int*)d_in[2];
    const float* proj3  = (const float*)d_in[3];
    const int*   t3     = (const int*)d_in[4];
    float* out = (float*)d_out;

    const int N = in_sizes[1] / D;   // 4096
    const int M = 2 * N;             // 8192
    const int MT = M + 128;

    _Float16* ftile = (_Float16*)d_ws;                           // MT*D halfs
    _Float16* oh    = ftile + (size_t)MT * D;                    // (M/16)*4*256 halfs
    float* Spart    = (float*)(oh + (size_t)(M / 16) * 4 * 256); // CH*(M/128)*128*64
    float* E        = Spart + (size_t)CH * (M / 128) * 128 * 64; // M*64
    float* loss     = E + (size_t)M * 64;                        // M
    float* cls_freq = loss + M;                                  // 64

    hist_kernel<<<1, 1024, 0, stream>>>(t2, t3, cls_freq, N, M);
    norm_kernel<<<(MT + 3) / 4, 256, 0, stream>>>(protos, proj2, proj3, t2, t3,
                                                  ftile, oh, N, M);
    dim3 grid(M / 128, CH);
    sim_kernel<<<grid, 256, 0, stream>>>(ftile, oh, Spart, E, M);
    fin_kernel<<<(M + 3) / 4, 256, 0, stream>>>(t2, t3, cls_freq, Spart, E, loss, N, M);
    out_kernel<<<1, 1024, 0, stream>>>(loss, out, M);
}

// Round 10
// 53.251 us; speedup vs baseline: 1.4761x; 1.0233x over previous
//
#include <hip/hip_runtime.h>
#include <math.h>
#include <stdint.h>

#define D    128
#define CCLS 64
#define CH   8      // column chunks; grid = (M/128) x CH

typedef _Float16 f16x8 __attribute__((ext_vector_type(8)));
typedef _Float16 f16x4 __attribute__((ext_vector_type(4)));
typedef float    f32x4 __attribute__((ext_vector_type(4)));

__device__ __forceinline__ float wave_reduce_sum(float v) {
    #pragma unroll
    for (int off = 32; off > 0; off >>= 1) v += __shfl_xor(v, off, 64);
    return v;
}

__device__ __forceinline__ void gload_lds16(const void* g, void* l) {
    __builtin_amdgcn_global_load_lds(
        (const __attribute__((address_space(1))) uint32_t*)g,
        (__attribute__((address_space(3))) uint32_t*)l, 16, 0, 0);
}

// --- normalize rows (feats ++ protos ++ zero-pad), fold sqrt(log2e/TAU),
//     cast f16, MFMA-tiled layout: elem(r,k) ->
//     ((r>>4)*16 + (k>>3))*128 + (r&15)*8 + (k&7).  One wave per row.
//     ALSO: first 2048 waves build one-hot tiles in 16x16x16 B-frag layout.
//     ALSO: block 0 computes the class histogram (LDS atomics) -> cls_freq.
__global__ void norm_kernel(const float* __restrict__ protos,
                            const float* __restrict__ proj2,
                            const float* __restrict__ proj3,
                            const int* __restrict__ t2, const int* __restrict__ t3,
                            _Float16* __restrict__ ftile,
                            _Float16* __restrict__ oh,
                            float* __restrict__ cls_freq, int N, int M) {
    const float SCL = 3.8017368953f;  // sqrt(10 * log2(e))
    int w = threadIdx.x >> 6;
    int lane = threadIdx.x & 63;
    int g = lane >> 4, li = lane & 15;
    int row = blockIdx.x * (blockDim.x >> 6) + w;
    const int MT = M + 128;

    if (blockIdx.x == 0) {             // fused class histogram (one block)
        __shared__ int h[CCLS];
        int t = threadIdx.x;
        if (t < CCLS) h[t] = 0;
        __syncthreads();
        for (int i = t; i < M; i += blockDim.x) {
            int lab = (i < N) ? t2[i] : t3[i - N];
            atomicAdd(&h[lab], 1);
        }
        __syncthreads();
        if (t < CCLS) cls_freq[t] = (float)h[t] + 1.0f + 1e-6f;
    }

    if (row < MT) {
        const float* src = nullptr;
        if (row < M)             src = (row < N) ? proj2 + (size_t)row * D
                                                 : proj3 + (size_t)(row - N) * D;
        else if (row < M + CCLS) src = protos + (size_t)(row - M) * D;
        float2 v = {0.f, 0.f};
        if (src) v = ((const float2*)src)[lane];
        float ss = wave_reduce_sum(v.x * v.x + v.y * v.y);
        float scale = src ? SCL / fmaxf(sqrtf(ss), 1e-12f) : 0.f;
        _Float16 h0 = (_Float16)(v.x * scale), h1 = (_Float16)(v.y * scale);
        int k0 = 2 * lane;
        size_t off = ((size_t)(row >> 4) * 16 + (k0 >> 3)) * 128 + (row & 15) * 8 + (k0 & 7);
        ftile[off] = h0; ftile[off + 1] = h1;
    }

    int wid = blockIdx.x * (blockDim.x >> 6) + w;
    if (wid < (M / 16) * 4) {
        int jt = wid >> 2, ct = wid & 3;
        int c = ct * 16 + li;
        f16x4 v;
        #pragma unroll
        for (int e = 0; e < 4; ++e) {
            int j = jt * 16 + 4 * g + e;
            int labj = (j < N) ? t2[j] : t3[j - N];
            v[e] = (labj == c) ? (_Float16)1.0f : (_Float16)0.0f;
        }
        *(f16x4*)(oh + ((size_t)(jt * 4 + ct)) * 256 + lane * 4) = v;
    }
}

// --- main: 128-row panel per block.x, 16-slice chunk per block.y.
//     8 waves x 16 rows (512 threads): same per-block staging cost as the
//     4-wave version but 4 waves/SIMD (16 waves/CU) to hide the serial
//     stage1 -> exp2 -> stage2 chain. B-tile (16KB) + oh-tile (8KB) staged
//     per slice via global_load_lds, double-buffered, shared block-wide.
//     Stage1: mfma_16x16x32_f16 (swapped) -> P (i=li, j=16n+4g+r);
//     exp2 -> cvt_pkrtz -> stage2 A-frag; stage2 16x16x16 vs onehot -> S.
//     Waves own disjoint rows => acc2 stored directly (no LDS reduce).
__global__ __launch_bounds__(512, 4)
void sim_kernel(const _Float16* __restrict__ ftile,
                const _Float16* __restrict__ ohtab,
                float* __restrict__ Spart, float* __restrict__ E, int M) {
    __shared__ _Float16 sbuf[2][12288];   // per buf: [0,8192)=B, [8192,12288)=oh

    const int panel = blockIdx.x;         // [0, M/128)
    const int chunk = blockIdx.y;         // [0, CH)
    const int t = threadIdx.x;
    const int w = t >> 6, lane = t & 63;  // w in [0,8)
    const int g = lane >> 4, li = lane & 15;
    const int lo = g * 128 + li * 8;
    const int rtA = panel * 8 + w;        // wave's single 16-row A tile
    const int nS = (M / 64) / CH;         // 16 slices per chunk
    const int sBase = chunk * nS;

    // A fragments: this wave's 16 rows x 128 k
    f16x8 a[4];
    #pragma unroll
    for (int kt = 0; kt < 4; ++kt)
        a[kt] = *(const f16x8*)(ftile + (size_t)rtA * 2048 + kt * 512 + lo);

    f32x4 acc2[4];                        // i = 16w+4g+r, c = 16nc+li
    #pragma unroll
    for (int nc = 0; nc < 4; ++nc)
        #pragma unroll
        for (int r = 0; r < 4; ++r) acc2[nc][r] = 0.f;

    // ---- staging: 24 x 1KB wave-issues per slice; wave w does j = 3w..3w+2
    #define STAGE(buf, s)                                                        \
        {                                                                        \
            const char* bsrc_ = (const char*)ftile + (size_t)(s) * 16384;        \
            const char* osrc_ = (const char*)ohtab + (size_t)(s) * 8192;         \
            char* dst_ = (char*)&sbuf[(buf)][0];                                 \
            _Pragma("unroll")                                                    \
            for (int q = 0; q < 3; ++q) {                                        \
                int j_ = w * 3 + q;                                              \
                const char* src_ = (j_ < 16)                                     \
                    ? bsrc_ + (size_t)j_ * 1024 + lane * 16                      \
                    : osrc_ + (size_t)(j_ - 16) * 1024 + lane * 16;              \
                gload_lds16(src_, dst_ + (size_t)j_ * 1024);                     \
            }                                                                    \
        }

    STAGE(0, sBase);
    __syncthreads();                       // compiler drains vmcnt before barrier
    int cur = 0;

    const int diagS = 2 * panel + (w >> 2);   // slice containing this wave's rows
    const int nDiag = w & 3;                  // n index of the diagonal sub-tile

    for (int si = 0; si < nS; ++si) {
        const int s = sBase + si;
        if (si + 1 < nS) STAGE(cur ^ 1, sBase + si + 1);

        const _Float16* Bl = &sbuf[cur][0];
        const _Float16* Ol = &sbuf[cur][8192];

        f32x4 acc1[4];
        #pragma unroll
        for (int n = 0; n < 4; ++n)
            #pragma unroll
            for (int r = 0; r < 4; ++r) acc1[n][r] = 0.f;

        #pragma unroll
        for (int kt = 0; kt < 4; ++kt) {
            f16x8 b[4];
            #pragma unroll
            for (int n = 0; n < 4; ++n)
                b[n] = *(const f16x8*)(Bl + n * 2048 + kt * 512 + lo);
            #pragma unroll
            for (int n = 0; n < 4; ++n)
                acc1[n] = __builtin_amdgcn_mfma_f32_16x16x32_f16(b[n], a[kt], acc1[n], 0, 0, 0);
        }

        // diagonal mask: wave-uniform slice test, static indices, cndmask
        if (s == diagS) {
            #pragma unroll
            for (int n = 0; n < 4; ++n)
                #pragma unroll
                for (int r = 0; r < 4; ++r)
                    acc1[n][r] = (n == nDiag && 4 * g + r == li) ? -1e5f : acc1[n][r];
        }

        #pragma unroll
        for (int n = 0; n < 4; ++n) {
            auto l2 = __builtin_amdgcn_cvt_pkrtz(__builtin_amdgcn_exp2f(acc1[n][0]),
                                                 __builtin_amdgcn_exp2f(acc1[n][1]));
            auto h2 = __builtin_amdgcn_cvt_pkrtz(__builtin_amdgcn_exp2f(acc1[n][2]),
                                                 __builtin_amdgcn_exp2f(acc1[n][3]));
            f16x4 pa; pa.x = l2.x; pa.y = l2.y; pa.z = h2.x; pa.w = h2.y;
            #pragma unroll
            for (int nc = 0; nc < 4; ++nc) {
                f16x4 ohf = *(const f16x4*)(Ol + (n * 4 + nc) * 256 + lane * 4);
                acc2[nc] = __builtin_amdgcn_mfma_f32_16x16x16f16(pa, ohf, acc2[nc], 0, 0, 0);
            }
        }

        __syncthreads();                   // drains stage loads + LDS reads
        cur ^= 1;
    }

    // store this wave's 16x64 partial directly (rows disjoint per wave)
    {
        float* dst = Spart + ((size_t)chunk * gridDim.x + panel) * (128 * 64);
        #pragma unroll
        for (int nc = 0; nc < 4; ++nc)
            #pragma unroll
            for (int r = 0; r < 4; ++r)
                dst[(size_t)(16 * w + 4 * g + r) * 64 + nc * 16 + li] = acc2[nc][r];
    }

    // proto slice: chunk-0 blocks, all 8 waves (disjoint rows) -> E[i][c]
    if (chunk == 0) {
        const int rbp = M >> 4;
        f32x4 accp[4];
        #pragma unroll
        for (int n = 0; n < 4; ++n)
            #pragma unroll
            for (int r = 0; r < 4; ++r) accp[n][r] = 0.f;
        #pragma unroll
        for (int kt = 0; kt < 4; ++kt) {
            f16x8 b[4];
            #pragma unroll
            for (int n = 0; n < 4; ++n)
                b[n] = *(const f16x8*)(ftile + (size_t)(rbp + n) * 2048 + kt * 512 + lo);
            #pragma unroll
            for (int n = 0; n < 4; ++n)
                accp[n] = __builtin_amdgcn_mfma_f32_16x16x32_f16(b[n], a[kt], accp[n], 0, 0, 0);
        }
        #pragma unroll
        for (int n = 0; n < 4; ++n)
            #pragma unroll
            for (int r = 0; r < 4; ++r)
                E[(size_t)(panel * 128 + 16 * w + li) * 64 + n * 16 + 4 * g + r]
                    = __builtin_amdgcn_exp2f(accp[n][r]);
    }
}

// --- per-row loss: one wave per row, lane = class ---------------------------
__global__ void fin_kernel(const int* __restrict__ t2, const int* __restrict__ t3,
                           const float* __restrict__ cls_freq,
                           const float* __restrict__ Spart, const float* __restrict__ E,
                           float* __restrict__ loss, int N, int M) {
    int w = threadIdx.x >> 6, lane = threadIdx.x & 63;
    int i = blockIdx.x * (blockDim.x >> 6) + w;
    if (i >= M) return;
    const int panel = i >> 7, lrow = i & 127;
    const size_t pbase = (size_t)panel * (128 * 64) + (size_t)lrow * 64 + lane;
    const size_t cstride = (size_t)(M / 128) * (128 * 64);
    float s = 0.f;
    #pragma unroll
    for (int k = 0; k < CH; ++k) s += Spart[pbase + (size_t)k * cstride];
    float ev = E[(size_t)i * 64 + lane];
    float fr = cls_freq[lane];
    float sumS  = wave_reduce_sum(s);
    float sumEw = wave_reduce_sum(ev / fr);
    int lab = (i < N) ? t2[i] : t3[i - N];
    float nmr = __shfl(s + ev, lab, 64);
    float fl  = __shfl(fr, lab, 64);
    float denom = sumS / fl + sumEw;
    if (lane == 0) loss[i] = logf(denom + 1e-12f) - logf(nmr);
}

// --- mean reduction: one block ----------------------------------------------
__global__ void out_kernel(const float* __restrict__ loss, float* __restrict__ out, int M) {
    float s = 0.f;
    for (int i = threadIdx.x; i < M; i += 1024) s += loss[i];
    s = wave_reduce_sum(s);
    __shared__ float ws_[16];
    if ((threadIdx.x & 63) == 0) ws_[threadIdx.x >> 6] = s;
    __syncthreads();
    if (threadIdx.x == 0) {
        float t = 0.f;
        for (int k = 0; k < 16; ++k) t += ws_[k];
        out[0] = t / (float)M;
    }
}

extern "C" void kernel_launch(void* const* d_in, const int* in_sizes, int n_in,
                              void* d_out, int out_size, void* d_ws, size_t ws_size,
                              hipStream_t stream) {
    const float* protos = (const float*)d_in[0];
    const float* proj2  = (const float*)d_in[1];
    const int*   t2     = (const int*)d_in[2];
    const float* proj3  = (const float*)d_in[3];
    const int*   t3     = (const int*)d_in[4];
    float* out = (float*)d_out;

    const int N = in_sizes[1] / D;   // 4096
    const int M = 2 * N;             // 8192
    const int MT = M + 128;

    _Float16* ftile = (_Float16*)d_ws;                           // MT*D halfs
    _Float16* oh    = ftile + (size_t)MT * D;                    // (M/16)*4*256 halfs
    float* Spart    = (float*)(oh + (size_t)(M / 16) * 4 * 256); // CH*(M/128)*128*64
    float* E        = Spart + (size_t)CH * (M / 128) * 128 * 64; // M*64
    float* loss     = E + (size_t)M * 64;                        // M
    float* cls_freq = loss + M;                                  // 64

    norm_kernel<<<(MT + 3) / 4, 256, 0, stream>>>(protos, proj2, proj3, t2, t3,
                                                  ftile, oh, cls_freq, N, M);
    dim3 grid(M / 128, CH);
    sim_kernel<<<grid, 512, 0, stream>>>(ftile, oh, Spart, E, M);
    fin_kernel<<<(M + 3) / 4, 256, 0, stream>>>(t2, t3, cls_freq, Spart, E, loss, N, M);
    out_kernel<<<1, 1024, 0, stream>>>(loss, out, M);
}

// Round 11
// 39.594 us; speedup vs baseline: 1.9852x; 1.3449x over previous
//
#include <hip/hip_runtime.h>
#include <math.h>
#include <stdint.h>

#define D    128
#define CCLS 64
#define CH   8      // column chunks; grid = (M/128) x CH

typedef _Float16 f16x8 __attribute__((ext_vector_type(8)));
typedef float    f32x4 __attribute__((ext_vector_type(4)));

__device__ __forceinline__ float wave_reduce_sum(float v) {
    #pragma unroll
    for (int off = 32; off > 0; off >>= 1) v += __shfl_xor(v, off, 64);
    return v;
}

__device__ __forceinline__ void gload_lds16(const void* g, void* l) {
    __builtin_amdgcn_global_load_lds(
        (const __attribute__((address_space(1))) uint32_t*)g,
        (__attribute__((address_space(3))) uint32_t*)l, 16, 0, 0);
}
__device__ __forceinline__ void gload_lds4(const void* g, void* l) {
    __builtin_amdgcn_global_load_lds(
        (const __attribute__((address_space(1))) uint32_t*)g,
        (__attribute__((address_space(3))) uint32_t*)l, 4, 0, 0);
}

// --- normalize rows (feats ++ protos ++ zero-pad), fold sqrt(log2e/TAU),
//     cast f16, MFMA-tiled layout: elem(r,k) ->
//     ((r>>4)*16 + (k>>3))*128 + (r&15)*8 + (k&7).  One wave per row.
//     ALSO: block 0 does the class histogram + zeroes loss_sum;
//     ALSO: materializes labs[] = concat(t2, t3) for staging/fin.
__global__ void norm_kernel(const float* __restrict__ protos,
                            const float* __restrict__ proj2,
                            const float* __restrict__ proj3,
                            const int* __restrict__ t2, const int* __restrict__ t3,
                            _Float16* __restrict__ ftile, int* __restrict__ labs,
                            float* __restrict__ cls_freq, float* __restrict__ loss_sum,
                            int N, int M) {
    const float SCL = 3.8017368953f;  // sqrt(10 * log2(e))
    int w = threadIdx.x >> 6;
    int lane = threadIdx.x & 63;
    int row = blockIdx.x * (blockDim.x >> 6) + w;
    const int MT = M + 128;

    if (blockIdx.x == 0) {             // fused class histogram (one block)
        __shared__ int h[CCLS];
        int t = threadIdx.x;
        if (t < CCLS) h[t] = 0;
        if (t == 0) loss_sum[0] = 0.f;
        __syncthreads();
        for (int i = t; i < M; i += blockDim.x) {
            int lab = (i < N) ? t2[i] : t3[i - N];
            atomicAdd(&h[lab], 1);
        }
        __syncthreads();
        if (t < CCLS) cls_freq[t] = (float)h[t] + 1.0f + 1e-6f;
    }

    if (row < MT) {
        const float* src = nullptr;
        if (row < M)             src = (row < N) ? proj2 + (size_t)row * D
                                                 : proj3 + (size_t)(row - N) * D;
        else if (row < M + CCLS) src = protos + (size_t)(row - M) * D;
        float2 v = {0.f, 0.f};
        if (src) v = ((const float2*)src)[lane];
        float ss = wave_reduce_sum(v.x * v.x + v.y * v.y);
        float scale = src ? SCL / fmaxf(sqrtf(ss), 1e-12f) : 0.f;
        _Float16 h0 = (_Float16)(v.x * scale), h1 = (_Float16)(v.y * scale);
        int k0 = 2 * lane;
        size_t off = ((size_t)(row >> 4) * 16 + (k0 >> 3)) * 128 + (row & 15) * 8 + (k0 & 7);
        ftile[off] = h0; ftile[off + 1] = h1;
        if (row < M && lane == 0)
            labs[row] = (row < N) ? t2[row] : t3[row - N];
    }
}

// --- main: 128-row panel per block.x, 16-slice chunk per block.y.
//     8 waves x 16 rows (512 threads). Per slice: B-tile (16KB) + labels
//     (256B) staged via global_load_lds, double-buffered, block-shared.
//     Stage1: mfma_16x16x32_f16 (swapped) -> P with i = lane&15 (row is
//     LANE-LOCAL) -> both loss reductions are per-lane scalar accumulators:
//     rd += e;  rn += (clab_j == rl) ? e : 0   (VALU pipe, overlaps MFMA).
//     NO stage2 matmul, NO one-hot, NO S/E round-trip. Proto slice fused
//     the same way in chunk 0 (rp += e/freq_c, reciprocal-weighted).
__global__ __launch_bounds__(512, 4)
void sim_kernel(const _Float16* __restrict__ ftile,
                const int* __restrict__ labs,
                const float* __restrict__ cls_freq,
                float* __restrict__ nPart, float* __restrict__ dPart,
                float* __restrict__ rp, int M) {
    __shared__ _Float16 sbuf[2][8320];   // per buf: 16KB B-tile + 256B labels

    const int panel = blockIdx.x;         // [0, M/128)
    const int chunk = blockIdx.y;         // [0, CH)
    const int t = threadIdx.x;
    const int w = t >> 6, lane = t & 63;  // w in [0,8)
    const int g = lane >> 4, li = lane & 15;
    const int lo = g * 128 + li * 8;
    const int rtA = panel * 8 + w;        // wave's single 16-row A tile
    const int nS = (M / 64) / CH;         // 16 slices per chunk
    const int sBase = chunk * nS;
    const int row = panel * 128 + 16 * w + li;
    const int rl = labs[row];             // this lane's row label

    // A fragments: this wave's 16 rows x 128 k
    f16x8 a[4];
    #pragma unroll
    for (int kt = 0; kt < 4; ++kt)
        a[kt] = *(const f16x8*)(ftile + (size_t)rtA * 2048 + kt * 512 + lo);

    float rn = 0.f, rd = 0.f;             // per-lane row sums (row = li)

    // ---- staging: 16 x 1KB B issues (2 per wave) + 256B labels (wave 0)
    #define STAGE(buf, s)                                                        \
        {                                                                        \
            const char* bsrc_ = (const char*)ftile + (size_t)(s) * 16384;        \
            char* dst_ = (char*)&sbuf[(buf)][0];                                 \
            _Pragma("unroll")                                                    \
            for (int q = 0; q < 2; ++q) {                                        \
                int j_ = w * 2 + q;                                              \
                gload_lds16(bsrc_ + (size_t)j_ * 1024 + lane * 16,               \
                            dst_ + (size_t)j_ * 1024);                           \
            }                                                                    \
            if (w == 0)                                                          \
                gload_lds4((const char*)labs + (size_t)(s) * 256 + lane * 4,     \
                           dst_ + 16384);                                        \
        }

    STAGE(0, sBase);
    __syncthreads();                       // compiler drains vmcnt before barrier
    int cur = 0;

    const int diagS = 2 * panel + (w >> 2);   // slice containing this wave's rows
    const int nDiag = w & 3;                  // n index of the diagonal sub-tile

    for (int si = 0; si < nS; ++si) {
        const int s = sBase + si;
        if (si + 1 < nS) STAGE(cur ^ 1, sBase + si + 1);

        const _Float16* Bl = &sbuf[cur][0];
        const int* clabL = (const int*)&sbuf[cur][8192];

        f32x4 acc1[4];
        #pragma unroll
        for (int n = 0; n < 4; ++n)
            #pragma unroll
            for (int r = 0; r < 4; ++r) acc1[n][r] = 0.f;

        #pragma unroll
        for (int kt = 0; kt < 4; ++kt) {
            f16x8 b[4];
            #pragma unroll
            for (int n = 0; n < 4; ++n)
                b[n] = *(const f16x8*)(Bl + n * 2048 + kt * 512 + lo);
            #pragma unroll
            for (int n = 0; n < 4; ++n)
                acc1[n] = __builtin_amdgcn_mfma_f32_16x16x32_f16(b[n], a[kt], acc1[n], 0, 0, 0);
        }

        // diagonal mask: wave-uniform slice test, static indices, cndmask
        if (s == diagS) {
            #pragma unroll
            for (int n = 0; n < 4; ++n)
                #pragma unroll
                for (int r = 0; r < 4; ++r)
                    acc1[n][r] = (n == nDiag && 4 * g + r == li) ? -1e5f : acc1[n][r];
        }

        // scalar epilogue: e = exp2(P); rd += e; rn += match ? e : 0
        #pragma unroll
        for (int n = 0; n < 4; ++n) {
            int4 c4 = *(const int4*)(clabL + 16 * n + 4 * g);
            float e0 = __builtin_amdgcn_exp2f(acc1[n][0]);
            float e1 = __builtin_amdgcn_exp2f(acc1[n][1]);
            float e2 = __builtin_amdgcn_exp2f(acc1[n][2]);
            float e3 = __builtin_amdgcn_exp2f(acc1[n][3]);
            rd += e0 + e1 + e2 + e3;
            rn += (c4.x == rl) ? e0 : 0.f;
            rn += (c4.y == rl) ? e1 : 0.f;
            rn += (c4.z == rl) ? e2 : 0.f;
            rn += (c4.w == rl) ? e3 : 0.f;
        }

        __syncthreads();                   // drains stage loads + LDS reads
        cur ^= 1;
    }

    // proto slice (chunk 0 only): fused the same way; rp = sum_c e/freq_c
    float rpacc = 0.f;
    if (chunk == 0) {
        const int rbp = M >> 4;
        f32x4 accp[4];
        #pragma unroll
        for (int n = 0; n < 4; ++n)
            #pragma unroll
            for (int r = 0; r < 4; ++r) accp[n][r] = 0.f;
        #pragma unroll
        for (int kt = 0; kt < 4; ++kt) {
            f16x8 b[4];
            #pragma unroll
            for (int n = 0; n < 4; ++n)
                b[n] = *(const f16x8*)(ftile + (size_t)(rbp + n) * 2048 + kt * 512 + lo);
            #pragma unroll
            for (int n = 0; n < 4; ++n)
                accp[n] = __builtin_amdgcn_mfma_f32_16x16x32_f16(b[n], a[kt], accp[n], 0, 0, 0);
        }
        #pragma unroll
        for (int n = 0; n < 4; ++n) {
            f32x4 fr = *(const f32x4*)(cls_freq + 16 * n + 4 * g);
            const int c0 = 16 * n + 4 * g;
            float e0 = __builtin_amdgcn_exp2f(accp[n][0]);
            float e1 = __builtin_amdgcn_exp2f(accp[n][1]);
            float e2 = __builtin_amdgcn_exp2f(accp[n][2]);
            float e3 = __builtin_amdgcn_exp2f(accp[n][3]);
            rpacc += e0 / fr[0] + e1 / fr[1] + e2 / fr[2] + e3 / fr[3];
            rn += (c0 + 0 == rl) ? e0 : 0.f;
            rn += (c0 + 1 == rl) ? e1 : 0.f;
            rn += (c0 + 2 == rl) ? e2 : 0.f;
            rn += (c0 + 3 == rl) ? e3 : 0.f;
        }
    }

    // reduce over the 4 lane-groups (same row li), then 16 coalesced stores
    rn += __shfl_xor(rn, 16, 64); rn += __shfl_xor(rn, 32, 64);
    rd += __shfl_xor(rd, 16, 64); rd += __shfl_xor(rd, 32, 64);
    if (chunk == 0) {
        rpacc += __shfl_xor(rpacc, 16, 64); rpacc += __shfl_xor(rpacc, 32, 64);
    }
    if (lane < 16) {
        nPart[(size_t)chunk * M + row] = rn;
        dPart[(size_t)chunk * M + row] = rd;
        if (chunk == 0) rp[row] = rpacc;
    }
}

// --- per-row loss + mean accumulate ------------------------------------------
__global__ void fin_kernel(const int* __restrict__ labs,
                           const float* __restrict__ cls_freq,
                           const float* __restrict__ nPart,
                           const float* __restrict__ dPart,
                           const float* __restrict__ rp,
                           float* __restrict__ loss_sum, int M) {
    int i = blockIdx.x * blockDim.x + threadIdx.x;
    float l = 0.f;
    if (i < M) {
        float rnT = 0.f, rdT = 0.f;
        #pragma unroll
        for (int ch = 0; ch < CH; ++ch) {
            rnT += nPart[(size_t)ch * M + i];
            rdT += dPart[(size_t)ch * M + i];
        }
        float denom = rdT / cls_freq[labs[i]] + rp[i];
        l = logf(denom + 1e-12f) - logf(rnT);
    }
    l = wave_reduce_sum(l);
    __shared__ float ws_[4];
    if ((threadIdx.x & 63) == 0) ws_[threadIdx.x >> 6] = l;
    __syncthreads();
    if (threadIdx.x == 0)
        atomicAdd(loss_sum, ws_[0] + ws_[1] + ws_[2] + ws_[3]);
}

__global__ void out_kernel(const float* __restrict__ loss_sum,
                           float* __restrict__ out, int M) {
    out[0] = loss_sum[0] / (float)M;
}

extern "C" void kernel_launch(void* const* d_in, const int* in_sizes, int n_in,
                              void* d_out, int out_size, void* d_ws, size_t ws_size,
                              hipStream_t stream) {
    const float* protos = (const float*)d_in[0];
    const float* proj2  = (const float*)d_in[1];
    const int*   t2     = (const int*)d_in[2];
    const float* proj3  = (const float*)d_in[3];
    const int*   t3     = (const int*)d_in[4];
    float* out = (float*)d_out;

    const int N = in_sizes[1] / D;   // 4096
    const int M = 2 * N;             // 8192
    const int MT = M + 128;

    _Float16* ftile = (_Float16*)d_ws;                 // MT*D halfs (1KB-tiled)
    int*   labs     = (int*)(ftile + (size_t)MT * D);  // M ints
    float* cls_freq = (float*)(labs + M);              // 64
    float* nPart    = cls_freq + CCLS;                 // CH*M
    float* dPart    = nPart + (size_t)CH * M;          // CH*M
    float* rp       = dPart + (size_t)CH * M;          // M
    float* loss_sum = rp + M;                          // 1

    norm_kernel<<<(MT + 3) / 4, 256, 0, stream>>>(protos, proj2, proj3, t2, t3,
                                                  ftile, labs, cls_freq, loss_sum, N, M);
    dim3 grid(M / 128, CH);
    sim_kernel<<<grid, 512, 0, stream>>>(ftile, labs, cls_freq, nPart, dPart, rp, M);
    fin_kernel<<<(M + 255) / 256, 256, 0, stream>>>(labs, cls_freq, nPart, dPart, rp,
                                                    loss_sum, M);
    out_kernel<<<1, 1, 0, stream>>>(loss_sum, out, M);
}

// Round 12
// 38.163 us; speedup vs baseline: 2.0596x; 1.0375x over previous
//
#include <hip/hip_runtime.h>
#include <math.h>
#include <stdint.h>

#define D    128
#define CCLS 64
#define CH   16     // column chunks; grid = (M/128) x CH

typedef _Float16 f16x8 __attribute__((ext_vector_type(8)));
typedef float    f32x4 __attribute__((ext_vector_type(4)));

__device__ __forceinline__ float wave_reduce_sum(float v) {
    #pragma unroll
    for (int off = 32; off > 0; off >>= 1) v += __shfl_xor(v, off, 64);
    return v;
}

__device__ __forceinline__ void gload_lds16(const void* g, void* l) {
    __builtin_amdgcn_global_load_lds(
        (const __attribute__((address_space(1))) uint32_t*)g,
        (__attribute__((address_space(3))) uint32_t*)l, 16, 0, 0);
}
__device__ __forceinline__ void gload_lds4(const void* g, void* l) {
    __builtin_amdgcn_global_load_lds(
        (const __attribute__((address_space(1))) uint32_t*)g,
        (__attribute__((address_space(3))) uint32_t*)l, 4, 0, 0);
}

// --- normalize rows (feats ++ protos ++ zero-pad), fold sqrt(log2e/TAU),
//     cast f16, MFMA-tiled layout: elem(r,k) ->
//     ((r>>4)*16 + (k>>3))*128 + (r&15)*8 + (k&7).  One wave per row.
//     ALSO: block 0 does the class histogram + zeroes loss_sum;
//     ALSO: materializes labs[] = concat(t2, t3).
__global__ void norm_kernel(const float* __restrict__ protos,
                            const float* __restrict__ proj2,
                            const float* __restrict__ proj3,
                            const int* __restrict__ t2, const int* __restrict__ t3,
                            _Float16* __restrict__ ftile, int* __restrict__ labs,
                            float* __restrict__ cls_freq, float* __restrict__ loss_sum,
                            int N, int M) {
    const float SCL = 3.8017368953f;  // sqrt(10 * log2(e))
    int w = threadIdx.x >> 6;
    int lane = threadIdx.x & 63;
    int row = blockIdx.x * (blockDim.x >> 6) + w;
    const int MT = M + 128;

    if (blockIdx.x == 0) {             // fused class histogram (one block)
        __shared__ int h[CCLS];
        int t = threadIdx.x;
        if (t < CCLS) h[t] = 0;
        if (t == 0) loss_sum[0] = 0.f;
        __syncthreads();
        for (int i = t; i < M; i += blockDim.x) {
            int lab = (i < N) ? t2[i] : t3[i - N];
            atomicAdd(&h[lab], 1);
        }
        __syncthreads();
        if (t < CCLS) cls_freq[t] = (float)h[t] + 1.0f + 1e-6f;
    }

    if (row < MT) {
        const float* src = nullptr;
        if (row < M)             src = (row < N) ? proj2 + (size_t)row * D
                                                 : proj3 + (size_t)(row - N) * D;
        else if (row < M + CCLS) src = protos + (size_t)(row - M) * D;
        float2 v = {0.f, 0.f};
        if (src) v = ((const float2*)src)[lane];
        float ss = wave_reduce_sum(v.x * v.x + v.y * v.y);
        float scale = src ? SCL / fmaxf(sqrtf(ss), 1e-12f) : 0.f;
        _Float16 h0 = (_Float16)(v.x * scale), h1 = (_Float16)(v.y * scale);
        int k0 = 2 * lane;
        size_t off = ((size_t)(row >> 4) * 16 + (k0 >> 3)) * 128 + (row & 15) * 8 + (k0 & 7);
        ftile[off] = h0; ftile[off + 1] = h1;
        if (row < M && lane == 0)
            labs[row] = (row < N) ? t2[row] : t3[row - N];
    }
}

// --- main: 128-row panel per block.x, 8-slice chunk per block.y.
//     4 waves x 32 rows (256 threads): HALVES the per-CU LDS-read demand
//     vs 8x16 (every wave reads the full 16KB B-tile per slice; LDS BW was
//     the R11 limiter at ~1GB total reads). B-tile + labels staged via
//     global_load_lds, double-buffered. Swapped MFMA keeps row lane-local:
//     rd/rn are per-lane scalar accumulators on the VALU pipe.
__global__ __launch_bounds__(256, 4)
void sim_kernel(const _Float16* __restrict__ ftile,
                const int* __restrict__ labs,
                const float* __restrict__ cls_freq,
                float* __restrict__ nPart, float* __restrict__ dPart,
                float* __restrict__ rp, int M) {
    __shared__ _Float16 sbuf[2][8320];   // per buf: 16KB B-tile + 256B labels

    const int panel = blockIdx.x;         // [0, M/128)
    const int chunk = blockIdx.y;         // [0, CH)
    const int t = threadIdx.x;
    const int w = t >> 6, lane = t & 63;  // w in [0,4)
    const int g = lane >> 4, li = lane & 15;
    const int lo = g * 128 + li * 8;
    const int rtA = panel * 8 + w * 2;    // wave's two 16-row A tiles
    const int nS = (M / 64) / CH;         // 8 slices per chunk
    const int sBase = chunk * nS;
    const int row0 = panel * 128 + 32 * w + li;   // lane's two rows: row0, row0+16
    const int rl0 = labs[row0];
    const int rl1 = labs[row0 + 16];

    // A fragments: this wave's 32 rows x 128 k
    f16x8 a[2][4];
    #pragma unroll
    for (int m = 0; m < 2; ++m)
        #pragma unroll
        for (int kt = 0; kt < 4; ++kt)
            a[m][kt] = *(const f16x8*)(ftile + (size_t)(rtA + m) * 2048 + kt * 512 + lo);

    float rn[2] = {0.f, 0.f}, rd[2] = {0.f, 0.f};
    float rpacc[2] = {0.f, 0.f};

    // ---- staging: 16 x 1KB B issues (4 per wave) + 256B labels (wave 0)
    #define STAGE(buf, s)                                                        \
        {                                                                        \
            const char* bsrc_ = (const char*)ftile + (size_t)(s) * 16384;        \
            char* dst_ = (char*)&sbuf[(buf)][0];                                 \
            _Pragma("unroll")                                                    \
            for (int q = 0; q < 4; ++q) {                                        \
                int j_ = w * 4 + q;                                              \
                gload_lds16(bsrc_ + (size_t)j_ * 1024 + lane * 16,               \
                            dst_ + (size_t)j_ * 1024);                           \
            }                                                                    \
            if (w == 0)                                                          \
                gload_lds4((const char*)labs + (size_t)(s) * 256 + lane * 4,     \
                           dst_ + 16384);                                        \
        }

    STAGE(0, sBase);
    __syncthreads();                       // compiler drains vmcnt before barrier
    int cur = 0;

    const int diagS = 2 * panel + (w >> 1);   // slice containing this wave's rows
    const int nD0 = 2 * (w & 1);              // diag n-index for m: n == nD0 + m

    for (int si = 0; si < nS; ++si) {
        const int s = sBase + si;
        if (si + 1 < nS) STAGE(cur ^ 1, sBase + si + 1);

        const _Float16* Bl = &sbuf[cur][0];
        const int* clabL = (const int*)&sbuf[cur][8192];

        f32x4 acc1[2][4];
        #pragma unroll
        for (int m = 0; m < 2; ++m)
            #pragma unroll
            for (int n = 0; n < 4; ++n)
                #pragma unroll
                for (int r = 0; r < 4; ++r) acc1[m][n][r] = 0.f;

        #pragma unroll
        for (int kt = 0; kt < 4; ++kt) {
            f16x8 b[4];
            #pragma unroll
            for (int n = 0; n < 4; ++n)
                b[n] = *(const f16x8*)(Bl + n * 2048 + kt * 512 + lo);
            #pragma unroll
            for (int m = 0; m < 2; ++m)
                #pragma unroll
                for (int n = 0; n < 4; ++n)
                    acc1[m][n] = __builtin_amdgcn_mfma_f32_16x16x32_f16(b[n], a[m][kt], acc1[m][n], 0, 0, 0);
        }

        // diagonal mask: wave-uniform slice test, static indices, cndmask
        if (s == diagS) {
            #pragma unroll
            for (int m = 0; m < 2; ++m)
                #pragma unroll
                for (int n = 0; n < 4; ++n)
                    #pragma unroll
                    for (int r = 0; r < 4; ++r)
                        acc1[m][n][r] = (n == nD0 + m && 4 * g + r == li)
                                        ? -1e5f : acc1[m][n][r];
        }

        // scalar epilogue: e = exp2(P); rd += e; rn += match ? e : 0
        #pragma unroll
        for (int n = 0; n < 4; ++n) {
            int4 c4 = *(const int4*)(clabL + 16 * n + 4 * g);
            #pragma unroll
            for (int m = 0; m < 2; ++m) {
                float e0 = __builtin_amdgcn_exp2f(acc1[m][n][0]);
                float e1 = __builtin_amdgcn_exp2f(acc1[m][n][1]);
                float e2 = __builtin_amdgcn_exp2f(acc1[m][n][2]);
                float e3 = __builtin_amdgcn_exp2f(acc1[m][n][3]);
                const int rl = m ? rl1 : rl0;
                rd[m] += e0 + e1 + e2 + e3;
                rn[m] += (c4.x == rl) ? e0 : 0.f;
                rn[m] += (c4.y == rl) ? e1 : 0.f;
                rn[m] += (c4.z == rl) ? e2 : 0.f;
                rn[m] += (c4.w == rl) ? e3 : 0.f;
            }
        }

        __syncthreads();                   // drains stage loads + LDS reads
        cur ^= 1;
    }

    // proto slice (chunk 0 only): rp = sum_c e/freq_c; numer += e[lab]
    if (chunk == 0) {
        const int rbp = M >> 4;
        f32x4 accp[2][4];
        #pragma unroll
        for (int m = 0; m < 2; ++m)
            #pragma unroll
            for (int n = 0; n < 4; ++n)
                #pragma unroll
                for (int r = 0; r < 4; ++r) accp[m][n][r] = 0.f;
        #pragma unroll
        for (int kt = 0; kt < 4; ++kt) {
            f16x8 b[4];
            #pragma unroll
            for (int n = 0; n < 4; ++n)
                b[n] = *(const f16x8*)(ftile + (size_t)(rbp + n) * 2048 + kt * 512 + lo);
            #pragma unroll
            for (int m = 0; m < 2; ++m)
                #pragma unroll
                for (int n = 0; n < 4; ++n)
                    accp[m][n] = __builtin_amdgcn_mfma_f32_16x16x32_f16(b[n], a[m][kt], accp[m][n], 0, 0, 0);
        }
        #pragma unroll
        for (int n = 0; n < 4; ++n) {
            f32x4 fr = *(const f32x4*)(cls_freq + 16 * n + 4 * g);
            const int c0 = 16 * n + 4 * g;
            #pragma unroll
            for (int m = 0; m < 2; ++m) {
                float e0 = __builtin_amdgcn_exp2f(accp[m][n][0]);
                float e1 = __builtin_amdgcn_exp2f(accp[m][n][1]);
                float e2 = __builtin_amdgcn_exp2f(accp[m][n][2]);
                float e3 = __builtin_amdgcn_exp2f(accp[m][n][3]);
                const int rl = m ? rl1 : rl0;
                rpacc[m] += e0 / fr[0] + e1 / fr[1] + e2 / fr[2] + e3 / fr[3];
                rn[m] += (c0 + 0 == rl) ? e0 : 0.f;
                rn[m] += (c0 + 1 == rl) ? e1 : 0.f;
                rn[m] += (c0 + 2 == rl) ? e2 : 0.f;
                rn[m] += (c0 + 3 == rl) ? e3 : 0.f;
            }
        }
    }

    // reduce over the 4 lane-groups (same rows), then coalesced stores
    #pragma unroll
    for (int m = 0; m < 2; ++m) {
        rn[m] += __shfl_xor(rn[m], 16, 64); rn[m] += __shfl_xor(rn[m], 32, 64);
        rd[m] += __shfl_xor(rd[m], 16, 64); rd[m] += __shfl_xor(rd[m], 32, 64);
        if (chunk == 0) {
            rpacc[m] += __shfl_xor(rpacc[m], 16, 64);
            rpacc[m] += __shfl_xor(rpacc[m], 32, 64);
        }
    }
    if (lane < 16) {
        #pragma unroll
        for (int m = 0; m < 2; ++m) {
            const int rowm = row0 + 16 * m;
            nPart[(size_t)chunk * M + rowm] = rn[m];
            dPart[(size_t)chunk * M + rowm] = rd[m];
            if (chunk == 0) rp[rowm] = rpacc[m];
        }
    }
}

// --- per-row loss + mean accumulate ------------------------------------------
__global__ void fin_kernel(const int* __restrict__ labs,
                           const float* __restrict__ cls_freq,
                           const float* __restrict__ nPart,
                           const float* __restrict__ dPart,
                           const float* __restrict__ rp,
                           float* __restrict__ loss_sum, int M) {
    int i = blockIdx.x * blockDim.x + threadIdx.x;
    float l = 0.f;
    if (i < M) {
        float rnT = 0.f, rdT = 0.f;
        #pragma unroll
        for (int ch = 0; ch < CH; ++ch) {
            rnT += nPart[(size_t)ch * M + i];
            rdT += dPart[(size_t)ch * M + i];
        }
        float denom = rdT / cls_freq[labs[i]] + rp[i];
        l = logf(denom + 1e-12f) - logf(rnT);
    }
    l = wave_reduce_sum(l);
    __shared__ float ws_[4];
    if ((threadIdx.x & 63) == 0) ws_[threadIdx.x >> 6] = l;
    __syncthreads();
    if (threadIdx.x == 0)
        atomicAdd(loss_sum, ws_[0] + ws_[1] + ws_[2] + ws_[3]);
}

__global__ void out_kernel(const float* __restrict__ loss_sum,
                           float* __restrict__ out, int M) {
    out[0] = loss_sum[0] / (float)M;
}

extern "C" void kernel_launch(void* const* d_in, const int* in_sizes, int n_in,
                              void* d_out, int out_size, void* d_ws, size_t ws_size,
                              hipStream_t stream) {
    const float* protos = (const float*)d_in[0];
    const float* proj2  = (const float*)d_in[1];
    const int*   t2     = (const int*)d_in[2];
    const float* proj3  = (const float*)d_in[3];
    const int*   t3     = (const int*)d_in[4];
    float* out = (float*)d_out;

    const int N = in_sizes[1] / D;   // 4096
    const int M = 2 * N;             // 8192
    const int MT = M + 128;

    _Float16* ftile = (_Float16*)d_ws;                 // MT*D halfs (1KB-tiled)
    int*   labs     = (int*)(ftile + (size_t)MT * D);  // M ints
    float* cls_freq = (float*)(labs + M);              // 64
    float* nPart    = cls_freq + CCLS;                 // CH*M
    float* dPart    = nPart + (size_t)CH * M;          // CH*M
    float* rp       = dPart + (size_t)CH * M;          // M
    float* loss_sum = rp + M;                          // 1

    norm_kernel<<<(MT + 3) / 4, 256, 0, stream>>>(protos, proj2, proj3, t2, t3,
                                                  ftile, labs, cls_freq, loss_sum, N, M);
    dim3 grid(M / 128, CH);
    sim_kernel<<<grid, 256, 0, stream>>>(ftile, labs, cls_freq, nPart, dPart, rp, M);
    fin_kernel<<<(M + 255) / 256, 256, 0, stream>>>(labs, cls_freq, nPart, dPart, rp,
                                                    loss_sum, M);
    out_kernel<<<1, 1, 0, stream>>>(loss_sum, out, M);
}